// Round 4
// baseline (6842.622 us; speedup 1.0000x reference)
//
#include <hip/hip_runtime.h>
#include <math.h>

#define B_  512
#define T_  256
#define I_  64
#define H_  512
#define G4  2048
#define K_  576   // 512 (h) + 64 (x)
#define HN  30
#define EPSf 1e-5f
#define GRP  8    // blocks per sync group (share 16 m-rows)
#define NGRP 32
#define BM   16
#define BJ   64

typedef __attribute__((ext_vector_type(8))) short short8;
typedef __attribute__((ext_vector_type(4))) float f32x4;

static __device__ __forceinline__ unsigned short f2bf(float f) {
    unsigned int u = __float_as_uint(f);
    u += 0x7fffu + ((u >> 16) & 1u);   // round-to-nearest-even
    return (unsigned short)(u >> 16);
}
static __device__ __forceinline__ float sigf(float x) {
    return __builtin_amdgcn_rcpf(1.0f + __expf(-x));
}
static __device__ __forceinline__ float tanh_f(float x) {
    float e = __expf(-2.0f * fabsf(x));
    float r = (1.0f - e) * __builtin_amdgcn_rcpf(1.0f + e);
    return copysignf(r, x);
}

// ---------------------------------------------------------------- pack / init
__global__ void pack_kernel(const float* __restrict__ x, const float* __restrict__ Wih,
                            const float* __restrict__ Whh, const float* __restrict__ bih,
                            const float* __restrict__ bhh, const float* __restrict__ l1w,
                            unsigned short* __restrict__ Wp, unsigned short* __restrict__ xb,
                            float* __restrict__ bias, unsigned short* __restrict__ hb,
                            float* __restrict__ a1p, unsigned short* __restrict__ wl1b,
                            unsigned int* __restrict__ arr) {
    const int stride = gridDim.x * blockDim.x;
    const int g0 = blockIdx.x * blockDim.x + threadIdx.x;
    // W packed: Wp[n][k], k<512 from W_hh, k>=512 from W_ih  (k-contiguous rows)
    for (int idx = g0; idx < G4 * K_; idx += stride) {
        int n = idx / K_, k = idx - n * K_;
        float v = (k < H_) ? Whh[n * H_ + k] : Wih[n * I_ + (k - H_)];
        Wp[idx] = f2bf(v);
    }
    // x transposed+bf16: xb[t][b][i]
    for (int idx = g0; idx < T_ * B_ * I_; idx += stride) {
        int t = idx / (B_ * I_);
        int r = idx - t * (B_ * I_);
        int b = r / I_, i = r - b * I_;
        xb[idx] = f2bf(x[((size_t)b * T_ + t) * I_ + i]);
    }
    for (int idx = g0; idx < G4; idx += stride) bias[idx] = bih[idx] + bhh[idx];
    for (int idx = g0; idx < B_ * H_; idx += stride) hb[idx] = 0;  // h0 = 0 (buffer 0)
    for (int idx = g0; idx < T_ * B_ * HN; idx += stride) a1p[idx] = 0.0f;
    // l1_w as bf16 [32][512], rows 30,31 zero
    for (int idx = g0; idx < 32 * H_; idx += stride) {
        int f = idx >> 9, k = idx & 511;
        wl1b[idx] = (f < HN) ? f2bf(l1w[f * H_ + k]) : 0;
    }
    for (int idx = g0; idx < NGRP * 32; idx += stride) arr[idx] = 0u;
}

// ---------------------------------------------------------------- persistent LSTM
// grid = 256 blocks (1/CU), 256 threads (4 waves). bid = jb*32 + mb.
// Group = 8 blocks with same mb (16 m-rows); wave w owns cols j0+w*16..+15, all
// 4 gates. B fragments (4 gates x 18 kc) live in 288 VGPRs for all 256 steps;
// c lives in 4 VGPRs/lane. Per step: group barrier -> A frags global->reg ->
// 72 MFMA -> cell update -> h store + l1 partial (1 MFMA + 4 atomics/lane).
// Spin is BOUNDED (hang-proof): a protocol failure produces wrong results,
// not a wedged GPU.
__global__ __launch_bounds__(256, 1) void lstm_kernel(
        const unsigned short* __restrict__ Wp, const unsigned short* __restrict__ xb,
        const float* __restrict__ bias, unsigned short* __restrict__ hb,
        float* __restrict__ a1p, const unsigned short* __restrict__ wl1b,
        unsigned int* __restrict__ arr) {
    __shared__ unsigned short hs[BM][72];   // h tile bf16 for the l1 A-fragment

    const int tid  = threadIdx.x;
    const int w    = tid >> 6;        // wave 0..3 -> col group
    const int lane = tid & 63;
    const int r    = lane & 15;       // A row / B col / D col index
    const int q    = lane >> 4;       // k-subchunk / D row group
    const int mb   = blockIdx.x & 31;
    const int jb   = blockIdx.x >> 5;
    const int m0   = mb * BM;
    const int j0   = jb * BJ;
    const int jcol = j0 + w * 16 + r;

    // ---- persistent B fragments (4 gates x 18 k-chunks) : 288 VGPRs
    short8 bfrag[4][18];
#pragma unroll
    for (int g = 0; g < 4; ++g)
#pragma unroll
        for (int kc = 0; kc < 18; ++kc)
            bfrag[g][kc] = *reinterpret_cast<const short8*>(
                Wp + (size_t)(g * H_ + jcol) * K_ + kc * 32 + q * 8);

    // l1 B fragment: wave covers f-half (w>>1), j-half (w&1)
    const short8 bl1 = *reinterpret_cast<const short8*>(
        wl1b + (size_t)((w >> 1) * 16 + r) * H_ + j0 + (w & 1) * 32 + q * 8);

    float bias_g[4];
#pragma unroll
    for (int g = 0; g < 4; ++g) bias_g[g] = bias[g * H_ + jcol];

    float c[4] = {0.f, 0.f, 0.f, 0.f};
    unsigned int* ctr = arr + mb * 32;   // one 128B-strided counter per group

#pragma unroll 1
    for (int t = 0; t < T_; ++t) {
        const unsigned short* hin = hb + (size_t)(t & 1) * B_ * H_;
        unsigned short* hout      = hb + (size_t)((t + 1) & 1) * B_ * H_;

        // x fragments: no dependency on the barrier, prefetch now
        const unsigned short* xr = xb + ((size_t)t * B_ + m0 + r) * I_ + q * 8;
        const short8 af16 = *reinterpret_cast<const short8*>(xr);
        const short8 af17 = *reinterpret_cast<const short8*>(xr + 32);

        // ---- group barrier: h(t-1) ready.  BOUNDED spin + s_sleep (hang-proof).
        if (t > 0) {
            if (tid == 0) {
                const unsigned target = (unsigned)(GRP * t);
                unsigned tries = 0;
                while (__hip_atomic_load(ctr, __ATOMIC_RELAXED,
                                         __HIP_MEMORY_SCOPE_AGENT) < target) {
                    if (++tries > 50000u) break;      // ~ms cap: fail loud, not hung
                    __builtin_amdgcn_s_sleep(2);
                }
            }
            __syncthreads();
            __builtin_amdgcn_fence(__ATOMIC_ACQUIRE, "agent");
        }

        // ---- A fragments: h rows m0..m0+15, direct global->reg
        short8 af[16];
#pragma unroll
        for (int kc = 0; kc < 16; ++kc)
            af[kc] = *reinterpret_cast<const short8*>(
                hin + (size_t)(m0 + r) * H_ + kc * 32 + q * 8);

        f32x4 acc[4];
#pragma unroll
        for (int g = 0; g < 4; ++g)
            acc[g] = (f32x4){bias_g[g], bias_g[g], bias_g[g], bias_g[g]};
#pragma unroll
        for (int kc = 0; kc < 16; ++kc)
#pragma unroll
            for (int g = 0; g < 4; ++g)
                acc[g] = __builtin_amdgcn_mfma_f32_16x16x32_bf16(af[kc], bfrag[g][kc], acc[g], 0, 0, 0);
#pragma unroll
        for (int g = 0; g < 4; ++g) {
            acc[g] = __builtin_amdgcn_mfma_f32_16x16x32_bf16(af16, bfrag[g][16], acc[g], 0, 0, 0);
            acc[g] = __builtin_amdgcn_mfma_f32_16x16x32_bf16(af17, bfrag[g][17], acc[g], 0, 0, 0);
        }

        // ---- cell update (c in registers); D mapping: col=r, row=q*4+rr
#pragma unroll
        for (int rr = 0; rr < 4; ++rr) {
            float ig = acc[0][rr], fg = acc[1][rr], gg = acc[2][rr], og = acc[3][rr];
            float cn = sigf(fg) * c[rr] + sigf(ig) * tanh_f(gg);
            c[rr] = cn;
            float hn = sigf(og) * tanh_f(cn);
            unsigned short hv = f2bf(hn);
            hout[(size_t)(m0 + q * 4 + rr) * H_ + jcol] = hv;
            hs[q * 4 + rr][w * 16 + r] = hv;
        }

        // ---- signal: h writes visible, then arrive
        __builtin_amdgcn_fence(__ATOMIC_RELEASE, "agent");
        __syncthreads();
        if (tid == 0)
            __hip_atomic_fetch_add(ctr, 1u, __ATOMIC_RELAXED, __HIP_MEMORY_SCOPE_AGENT);

        // ---- l1 partial (overlaps other blocks' sync): 1 MFMA + 4 atomics
        const short8 ah = *reinterpret_cast<const short8*>(&hs[r][(w & 1) * 32 + q * 8]);
        f32x4 d = __builtin_amdgcn_mfma_f32_16x16x32_bf16(ah, bl1, (f32x4){0.f, 0.f, 0.f, 0.f}, 0, 0, 0);
        const int fglob = (w >> 1) * 16 + r;
        if (fglob < HN) {
            float* dst = a1p + ((size_t)t * B_ + m0 + q * 4) * HN + fglob;
#pragma unroll
            for (int rr = 0; rr < 4; ++rr)
                atomicAdd(dst + rr * HN, d[rr]);
        }
    }
}

// ---------------------------------------------------------------- MLP head
static __device__ __forceinline__ void bn_relu30(float v[HN], const float* __restrict__ gamma,
                                                 const float* __restrict__ beta,
                                                 float (*pS)[HN], float (*pQ)[HN]) {
    float s0[HN], s1[HN];
#pragma unroll
    for (int f = 0; f < HN; ++f) { s0[f] = v[f]; s1[f] = v[f] * v[f]; }
#pragma unroll
    for (int off = 32; off >= 1; off >>= 1) {
#pragma unroll
        for (int f = 0; f < HN; ++f) {
            s0[f] += __shfl_xor(s0[f], off);
            s1[f] += __shfl_xor(s1[f], off);
        }
    }
    const int lane = threadIdx.x & 63, w = threadIdx.x >> 6;
    if (lane == 0) {
#pragma unroll
        for (int f = 0; f < HN; ++f) { pS[w][f] = s0[f]; pQ[w][f] = s1[f]; }
    }
    __syncthreads();
#pragma unroll
    for (int f = 0; f < HN; ++f) {
        float S = 0.f, Q = 0.f;
#pragma unroll
        for (int u = 0; u < 8; ++u) { S += pS[u][f]; Q += pQ[u][f]; }
        float m = S * (1.0f / 512.0f);
        float var = Q * (1.0f / 512.0f) - m * m;     // biased, matches jnp.mean
        float inv = 1.0f / sqrtf(var + EPSf);
        float tv = gamma[f] * (v[f] - m) * inv + beta[f];
        v[f] = fmaxf(tv, 0.f);
    }
    __syncthreads();
}

static __device__ __forceinline__ void layer30(float v[HN], const float* __restrict__ w) {
    float u[HN];
#pragma unroll
    for (int f = 0; f < HN; ++f) {
        float a = 0.f;
#pragma unroll
        for (int k = 0; k < HN; ++k) a = fmaf(v[k], w[f * HN + k], a);
        u[f] = a;
    }
#pragma unroll
    for (int f = 0; f < HN; ++f) v[f] = u[f];
}

__global__ __launch_bounds__(512) void mlp_kernel(
        const float* __restrict__ a1p, const float* __restrict__ l1b,
        const float* __restrict__ l2w, const float* __restrict__ l3w,
        const float* __restrict__ l4w, const float* __restrict__ l5w,
        const float* __restrict__ gamma, const float* __restrict__ beta,
        float* __restrict__ out) {
    const int t = blockIdx.x;
    const int b = threadIdx.x;
    __shared__ float pS[8][HN], pQ[8][HN];
    float v[HN];
    const float* src = a1p + ((size_t)t * B_ + b) * HN;
#pragma unroll
    for (int f = 0; f < HN; ++f) v[f] = src[f] + l1b[f];
    bn_relu30(v, gamma, beta, pS, pQ);
    layer30(v, l2w); bn_relu30(v, gamma, beta, pS, pQ);
    layer30(v, l3w); bn_relu30(v, gamma, beta, pS, pQ);
    layer30(v, l4w); bn_relu30(v, gamma, beta, pS, pQ);
    float o0 = 0.f, o1 = 0.f;
#pragma unroll
    for (int k = 0; k < HN; ++k) {
        o0 = fmaf(v[k], l5w[k], o0);
        o1 = fmaf(v[k], l5w[HN + k], o1);
    }
    out[(size_t)b * (2 * T_) + t]      = o0;   // out[b][0][t]
    out[(size_t)b * (2 * T_) + T_ + t] = o1;   // out[b][1][t]
}

// ---------------------------------------------------------------- launch
extern "C" void kernel_launch(void* const* d_in, const int* in_sizes, int n_in,
                              void* d_out, int out_size, void* d_ws, size_t ws_size,
                              hipStream_t stream) {
    const float* x    = (const float*)d_in[0];
    const float* Wih  = (const float*)d_in[1];
    const float* Whh  = (const float*)d_in[2];
    const float* bih  = (const float*)d_in[3];
    const float* bhh  = (const float*)d_in[4];
    const float* l1w  = (const float*)d_in[5];
    const float* l1b  = (const float*)d_in[6];
    const float* l2w  = (const float*)d_in[7];
    const float* l3w  = (const float*)d_in[8];
    const float* l4w  = (const float*)d_in[9];
    const float* l5w  = (const float*)d_in[10];
    const float* gam  = (const float*)d_in[11];
    const float* bet  = (const float*)d_in[12];
    float* out = (float*)d_out;

    char* ws = (char*)d_ws;
    unsigned short* Wp   = (unsigned short*)ws;  ws += (size_t)G4 * K_ * 2;        // 2.36 MB
    unsigned short* xb   = (unsigned short*)ws;  ws += (size_t)T_ * B_ * I_ * 2;   // 16.8 MB
    float*          bia  = (float*)ws;           ws += (size_t)G4 * 4;             // 8 KB
    unsigned short* hb   = (unsigned short*)ws;  ws += (size_t)2 * B_ * H_ * 2;    // 1 MB
    float*          a1p  = (float*)ws;           ws += (size_t)T_ * B_ * HN * 4;   // 15.7 MB
    unsigned short* wl1b = (unsigned short*)ws;  ws += (size_t)32 * H_ * 2;        // 32 KB
    unsigned int*   arr  = (unsigned int*)ws;    ws += (size_t)NGRP * 32 * 4;      // 4 KB

    pack_kernel<<<1024, 256, 0, stream>>>(x, Wih, Whh, bih, bhh, l1w,
                                          Wp, xb, bia, hb, a1p, wl1b, arr);
    lstm_kernel<<<GRP * NGRP, 256, 0, stream>>>(Wp, xb, bia, hb, a1p, wl1b, arr);
    mlp_kernel<<<T_, 512, 0, stream>>>(a1p, l1b, l2w, l3w, l4w, l5w, gam, bet, out);
}

// Round 5
// 1964.480 us; speedup vs baseline: 3.4832x; 3.4832x over previous
//
#include <hip/hip_runtime.h>
#include <math.h>

#define B_  512
#define T_  256
#define I_  64
#define H_  512
#define G4  2048
#define K_  576   // 512 (h) + 64 (x)
#define HN  30
#define EPSf 1e-5f
#define GRP  8    // blocks per sync group (share 16 m-rows)
#define NGRP 32
#define BM   16
#define BJ   64

typedef __attribute__((ext_vector_type(8))) short short8;
typedef __attribute__((ext_vector_type(4))) float f32x4;
typedef __attribute__((ext_vector_type(2))) unsigned long long ulong2_t;

static __device__ __forceinline__ unsigned short f2bf(float f) {
    unsigned int u = __float_as_uint(f);
    u += 0x7fffu + ((u >> 16) & 1u);   // round-to-nearest-even
    return (unsigned short)(u >> 16);
}
static __device__ __forceinline__ float sigf(float x) {
    return __builtin_amdgcn_rcpf(1.0f + __expf(-x));
}
static __device__ __forceinline__ float tanh_f(float x) {
    float e = __expf(-2.0f * fabsf(x));
    float r = (1.0f - e) * __builtin_amdgcn_rcpf(1.0f + e);
    return copysignf(r, x);
}

// ---------------------------------------------------------------- pack / init
__global__ void pack_kernel(const float* __restrict__ x, const float* __restrict__ Wih,
                            const float* __restrict__ Whh, const float* __restrict__ bih,
                            const float* __restrict__ bhh, const float* __restrict__ l1w,
                            unsigned short* __restrict__ Wp, unsigned short* __restrict__ xb,
                            float* __restrict__ bias, unsigned short* __restrict__ hb,
                            float* __restrict__ a1p, unsigned short* __restrict__ wl1b,
                            unsigned int* __restrict__ arr) {
    const int stride = gridDim.x * blockDim.x;
    const int g0 = blockIdx.x * blockDim.x + threadIdx.x;
    // W packed: Wp[n][k], k<512 from W_hh, k>=512 from W_ih  (k-contiguous rows)
    for (int idx = g0; idx < G4 * K_; idx += stride) {
        int n = idx / K_, k = idx - n * K_;
        float v = (k < H_) ? Whh[n * H_ + k] : Wih[n * I_ + (k - H_)];
        Wp[idx] = f2bf(v);
    }
    // x transposed+bf16: xb[t][b][i]
    for (int idx = g0; idx < T_ * B_ * I_; idx += stride) {
        int t = idx / (B_ * I_);
        int r = idx - t * (B_ * I_);
        int b = r / I_, i = r - b * I_;
        xb[idx] = f2bf(x[((size_t)b * T_ + t) * I_ + i]);
    }
    for (int idx = g0; idx < G4; idx += stride) bias[idx] = bih[idx] + bhh[idx];
    for (int idx = g0; idx < B_ * H_; idx += stride) hb[idx] = 0;  // h0 = 0 (buffer 0)
    for (int idx = g0; idx < T_ * B_ * HN; idx += stride) a1p[idx] = 0.0f;
    // l1_w as bf16 [32][512], rows 30,31 zero
    for (int idx = g0; idx < 32 * H_; idx += stride) {
        int f = idx >> 9, k = idx & 511;
        wl1b[idx] = (f < HN) ? f2bf(l1w[f * H_ + k]) : 0;
    }
    for (int idx = g0; idx < NGRP * 32; idx += stride) arr[idx] = 0u;
}

// ---------------------------------------------------------------- persistent LSTM
// grid = 256 blocks (1/CU), 256 threads (4 waves). bid = jb*32 + mb.
// Group = 8 blocks with same mb (16 m-rows). W lives in 288 VGPRs/lane, PINNED
// via asm so the compiler cannot sink the loads into the loop. h exchange is
// FENCE-FREE: agent-scope relaxed atomic stores/loads (sc0|sc1 -> coherence
// point), release ordering via s_waitcnt vmcnt(0) + barrier before the signal.
// Spin is bounded (hang-proof).
__global__ __launch_bounds__(256, 1) void lstm_kernel(
        const unsigned short* __restrict__ Wp, const unsigned short* __restrict__ xb,
        const float* __restrict__ bias, unsigned short* __restrict__ hb,
        float* __restrict__ a1p, const unsigned short* __restrict__ wl1b,
        unsigned int* __restrict__ arr) {
    __shared__ unsigned short hs[BM][72];   // fp-rounded h tile (bf16) for store + l1

    const int tid  = threadIdx.x;
    const int w    = tid >> 6;        // wave 0..3 -> col group
    const int lane = tid & 63;
    const int r    = lane & 15;       // A row / B col / D col index
    const int q    = lane >> 4;       // k-subchunk / D row group
    const int mb   = blockIdx.x & 31;
    const int jb   = blockIdx.x >> 5;
    const int m0   = mb * BM;
    const int j0   = jb * BJ;
    const int jcol = j0 + w * 16 + r;

    // ---- persistent B fragments (4 gates x 18 k-chunks) : 288 VGPRs, pinned
    short8 bfrag[4][18];
#pragma unroll
    for (int g = 0; g < 4; ++g)
#pragma unroll
        for (int kc = 0; kc < 18; ++kc) {
            bfrag[g][kc] = *reinterpret_cast<const short8*>(
                Wp + (size_t)(g * H_ + jcol) * K_ + kc * 32 + q * 8);
            asm volatile("" : "+v"(bfrag[g][kc]));   // opaque: cannot be remat'd
        }

    // l1 B fragment: wave covers f-half (w>>1), j-half (w&1)
    short8 bl1 = *reinterpret_cast<const short8*>(
        wl1b + (size_t)((w >> 1) * 16 + r) * H_ + j0 + (w & 1) * 32 + q * 8);
    asm volatile("" : "+v"(bl1));

    float bias_g[4];
#pragma unroll
    for (int g = 0; g < 4; ++g) bias_g[g] = bias[g * H_ + jcol];

    float c[4] = {0.f, 0.f, 0.f, 0.f};
    unsigned int* ctr = arr + mb * 32;   // one 128B-strided counter per group

    // store-phase decomposition: one 8B store per thread (16 rows x 16 segs)
    const int srow = tid >> 4, sseg = tid & 15;

#pragma unroll 1
    for (int t = 0; t < T_; ++t) {
        const unsigned short* hin = hb + (size_t)(t & 1) * B_ * H_;
        unsigned short* hout      = hb + (size_t)((t + 1) & 1) * B_ * H_;

        // x fragments: no dependency on the barrier, prefetch now (read-only data)
        const unsigned short* xr = xb + ((size_t)t * B_ + m0 + r) * I_ + q * 8;
        const short8 af16 = *reinterpret_cast<const short8*>(xr);
        const short8 af17 = *reinterpret_cast<const short8*>(xr + 32);

        // ---- group barrier: h(t-1) ready.  Bounded relaxed-atomic poll.
        if (t > 0) {
            if (tid == 0) {
                const unsigned target = (unsigned)(GRP * t);
                unsigned tries = 0;
                while (__hip_atomic_load(ctr, __ATOMIC_RELAXED,
                                         __HIP_MEMORY_SCOPE_AGENT) < target) {
                    if (++tries > 200000u) break;      // fail loud, never wedge
                    __builtin_amdgcn_s_sleep(1);
                }
            }
            __syncthreads();
            asm volatile("" ::: "memory");   // compiler fence: no hoisting of h loads
        }

        // ---- A fragments: h rows m0..m0+15 via agent-coherent 8B loads
        short8 af[16];
        {
            const unsigned long long* hrow = reinterpret_cast<const unsigned long long*>(
                hin + (size_t)(m0 + r) * H_);
#pragma unroll
            for (int kc = 0; kc < 16; ++kc) {
                ulong2_t u;
                u.x = __hip_atomic_load((unsigned long long*)(hrow + kc * 8 + q * 2),
                                        __ATOMIC_RELAXED, __HIP_MEMORY_SCOPE_AGENT);
                u.y = __hip_atomic_load((unsigned long long*)(hrow + kc * 8 + q * 2 + 1),
                                        __ATOMIC_RELAXED, __HIP_MEMORY_SCOPE_AGENT);
                af[kc] = __builtin_bit_cast(short8, u);
            }
        }

        f32x4 acc[4];
#pragma unroll
        for (int g = 0; g < 4; ++g)
            acc[g] = (f32x4){bias_g[g], bias_g[g], bias_g[g], bias_g[g]};
#pragma unroll
        for (int kc = 0; kc < 16; ++kc)
#pragma unroll
            for (int g = 0; g < 4; ++g)
                acc[g] = __builtin_amdgcn_mfma_f32_16x16x32_bf16(af[kc], bfrag[g][kc], acc[g], 0, 0, 0);
#pragma unroll
        for (int g = 0; g < 4; ++g) {
            acc[g] = __builtin_amdgcn_mfma_f32_16x16x32_bf16(af16, bfrag[g][16], acc[g], 0, 0, 0);
            acc[g] = __builtin_amdgcn_mfma_f32_16x16x32_bf16(af17, bfrag[g][17], acc[g], 0, 0, 0);
        }

        // ---- cell update (c in registers); D mapping: col=r, row=q*4+rr
#pragma unroll
        for (int rr = 0; rr < 4; ++rr) {
            float ig = acc[0][rr], fg = acc[1][rr], gg = acc[2][rr], og = acc[3][rr];
            float cn = sigf(fg) * c[rr] + sigf(ig) * tanh_f(gg);
            c[rr] = cn;
            float hn = sigf(og) * tanh_f(cn);
            hs[q * 4 + rr][w * 16 + r] = f2bf(hn);
        }
        __syncthreads();   // hs complete

        // ---- h store: one 8B agent-coherent store per thread
        {
            unsigned long long pv;
            __builtin_memcpy(&pv, &hs[srow][sseg * 4], 8);
            __hip_atomic_store((unsigned long long*)(hout + (size_t)(m0 + srow) * H_
                                                     + j0 + sseg * 4),
                               pv, __ATOMIC_RELAXED, __HIP_MEMORY_SCOPE_AGENT);
        }
        asm volatile("s_waitcnt vmcnt(0)" ::: "memory");   // stores acked at coherence pt
        __syncthreads();                                    // ...by ALL waves
        if (tid == 0)
            __hip_atomic_fetch_add(ctr, 1u, __ATOMIC_RELAXED, __HIP_MEMORY_SCOPE_AGENT);

        // ---- l1 partial (overlaps other blocks' sync): 1 MFMA + 4 atomics
        const short8 ah = *reinterpret_cast<const short8*>(&hs[r][(w & 1) * 32 + q * 8]);
        f32x4 d = __builtin_amdgcn_mfma_f32_16x16x32_bf16(ah, bl1, (f32x4){0.f, 0.f, 0.f, 0.f}, 0, 0, 0);
        const int fglob = (w >> 1) * 16 + r;
        if (fglob < HN) {
            float* dst = a1p + ((size_t)t * B_ + m0 + q * 4) * HN + fglob;
#pragma unroll
            for (int rr = 0; rr < 4; ++rr)
                atomicAdd(dst + rr * HN, d[rr]);
        }
    }
}

// ---------------------------------------------------------------- MLP head
static __device__ __forceinline__ void bn_relu30(float v[HN], const float* __restrict__ gamma,
                                                 const float* __restrict__ beta,
                                                 float (*pS)[HN], float (*pQ)[HN]) {
    float s0[HN], s1[HN];
#pragma unroll
    for (int f = 0; f < HN; ++f) { s0[f] = v[f]; s1[f] = v[f] * v[f]; }
#pragma unroll
    for (int off = 32; off >= 1; off >>= 1) {
#pragma unroll
        for (int f = 0; f < HN; ++f) {
            s0[f] += __shfl_xor(s0[f], off);
            s1[f] += __shfl_xor(s1[f], off);
        }
    }
    const int lane = threadIdx.x & 63, w = threadIdx.x >> 6;
    if (lane == 0) {
#pragma unroll
        for (int f = 0; f < HN; ++f) { pS[w][f] = s0[f]; pQ[w][f] = s1[f]; }
    }
    __syncthreads();
#pragma unroll
    for (int f = 0; f < HN; ++f) {
        float S = 0.f, Q = 0.f;
#pragma unroll
        for (int u = 0; u < 8; ++u) { S += pS[u][f]; Q += pQ[u][f]; }
        float m = S * (1.0f / 512.0f);
        float var = Q * (1.0f / 512.0f) - m * m;     // biased, matches jnp.mean
        float inv = 1.0f / sqrtf(var + EPSf);
        float tv = gamma[f] * (v[f] - m) * inv + beta[f];
        v[f] = fmaxf(tv, 0.f);
    }
    __syncthreads();
}

static __device__ __forceinline__ void layer30(float v[HN], const float* __restrict__ w) {
    float u[HN];
#pragma unroll
    for (int f = 0; f < HN; ++f) {
        float a = 0.f;
#pragma unroll
        for (int k = 0; k < HN; ++k) a = fmaf(v[k], w[f * HN + k], a);
        u[f] = a;
    }
#pragma unroll
    for (int f = 0; f < HN; ++f) v[f] = u[f];
}

__global__ __launch_bounds__(512) void mlp_kernel(
        const float* __restrict__ a1p, const float* __restrict__ l1b,
        const float* __restrict__ l2w, const float* __restrict__ l3w,
        const float* __restrict__ l4w, const float* __restrict__ l5w,
        const float* __restrict__ gamma, const float* __restrict__ beta,
        float* __restrict__ out) {
    const int t = blockIdx.x;
    const int b = threadIdx.x;
    __shared__ float pS[8][HN], pQ[8][HN];
    float v[HN];
    const float* src = a1p + ((size_t)t * B_ + b) * HN;
#pragma unroll
    for (int f = 0; f < HN; ++f) v[f] = src[f] + l1b[f];
    bn_relu30(v, gamma, beta, pS, pQ);
    layer30(v, l2w); bn_relu30(v, gamma, beta, pS, pQ);
    layer30(v, l3w); bn_relu30(v, gamma, beta, pS, pQ);
    layer30(v, l4w); bn_relu30(v, gamma, beta, pS, pQ);
    float o0 = 0.f, o1 = 0.f;
#pragma unroll
    for (int k = 0; k < HN; ++k) {
        o0 = fmaf(v[k], l5w[k], o0);
        o1 = fmaf(v[k], l5w[HN + k], o1);
    }
    out[(size_t)b * (2 * T_) + t]      = o0;   // out[b][0][t]
    out[(size_t)b * (2 * T_) + T_ + t] = o1;   // out[b][1][t]
}

// ---------------------------------------------------------------- launch
extern "C" void kernel_launch(void* const* d_in, const int* in_sizes, int n_in,
                              void* d_out, int out_size, void* d_ws, size_t ws_size,
                              hipStream_t stream) {
    const float* x    = (const float*)d_in[0];
    const float* Wih  = (const float*)d_in[1];
    const float* Whh  = (const float*)d_in[2];
    const float* bih  = (const float*)d_in[3];
    const float* bhh  = (const float*)d_in[4];
    const float* l1w  = (const float*)d_in[5];
    const float* l1b  = (const float*)d_in[6];
    const float* l2w  = (const float*)d_in[7];
    const float* l3w  = (const float*)d_in[8];
    const float* l4w  = (const float*)d_in[9];
    const float* l5w  = (const float*)d_in[10];
    const float* gam  = (const float*)d_in[11];
    const float* bet  = (const float*)d_in[12];
    float* out = (float*)d_out;

    char* ws = (char*)d_ws;
    unsigned short* Wp   = (unsigned short*)ws;  ws += (size_t)G4 * K_ * 2;        // 2.36 MB
    unsigned short* xb   = (unsigned short*)ws;  ws += (size_t)T_ * B_ * I_ * 2;   // 16.8 MB
    float*          bia  = (float*)ws;           ws += (size_t)G4 * 4;             // 8 KB
    unsigned short* hb   = (unsigned short*)ws;  ws += (size_t)2 * B_ * H_ * 2;    // 1 MB
    float*          a1p  = (float*)ws;           ws += (size_t)T_ * B_ * HN * 4;   // 15.7 MB
    unsigned short* wl1b = (unsigned short*)ws;  ws += (size_t)32 * H_ * 2;        // 32 KB
    unsigned int*   arr  = (unsigned int*)ws;    ws += (size_t)NGRP * 32 * 4;      // 4 KB

    pack_kernel<<<1024, 256, 0, stream>>>(x, Wih, Whh, bih, bhh, l1w,
                                          Wp, xb, bia, hb, a1p, wl1b, arr);
    lstm_kernel<<<GRP * NGRP, 256, 0, stream>>>(Wp, xb, bia, hb, a1p, wl1b, arr);
    mlp_kernel<<<T_, 512, 0, stream>>>(a1p, l1b, l2w, l3w, l4w, l5w, gam, bet, out);
}